// Round 6
// baseline (261.901 us; speedup 1.0000x reference)
//
#include <hip/hip_runtime.h>
#include <hip/hip_cooperative_groups.h>
#include <hip/hip_bf16.h>
#include <math.h>

namespace cg = cooperative_groups;

// ---- problem constants ----
#define SS 2304       // S = B*C*K*K
#define QSCALE 0.8329506128860126f  // log2(e)/sqrt(3)
#define TSPLIT 4
#define TCH 576       // SS / TSPLIT
#define NTASK 2592    // 36 nh * 18 schunk * 4 tc
#define MAXGRID 648

#if defined(__has_builtin)
#if __has_builtin(__builtin_amdgcn_exp2f)
#define EXP2(x) __builtin_amdgcn_exp2f(x)
#endif
#endif
#ifndef EXP2
#define EXP2(x) exp2f(x)
#endif

typedef short s8v __attribute__((ext_vector_type(8)));
typedef float f32x16 __attribute__((ext_vector_type(16)));

static __device__ __forceinline__ unsigned short f2b(float f) {
  __hip_bfloat16 h = __float2bfloat16(f);
  return __builtin_bit_cast(unsigned short, h);
}

struct Prm {
  const float *x, *ce, *pe, *ipw, *ipb, *opw, *opb, *ln1w, *ln1b;
  const float *f1w, *f1b, *f2w, *f2b, *ln2w, *ln2b, *linw, *linb;
  unsigned short *Qb, *Kb, *Vt;
  float4 *part;
  float *out;
};

// ============================================================
// Fused cooperative kernel: 3 phases separated by grid.sync().
// Grid is runtime-sized from the occupancy query (>=256, <=648);
// phase 2 is a grid-stride task loop so any grid size is correct.
// ============================================================
__global__ __launch_bounds__(256, 3) void fused(Prm p) {
  cg::grid_group grid = cg::this_grid();
  __shared__ __align__(16) unsigned short lds[4672];  // 9344 B, aliased/phase
  const int tid = threadIdx.x;
  const int bid = blockIdx.x;

  // ---------------- Phase 1: embed + QKV ----------------
  if (bid < 243) {
    float* lw = (float*)lds;           // 144 floats
    float* lb = (float*)lds + 144;     // 12 floats
    const int grp = bid / 81;          // 0=q 1=k 2=v (uniform per block)
    const int ib = bid % 81;
    for (int i = tid; i < 144; i += 256) lw[i] = p.ipw[grp * 144 + i];
    if (tid < 12) lb[tid] = p.ipb[grp * 12 + tid];
    __syncthreads();

    const int idx = ib * 256 + tid;    // n*2304 + s
    const int n = idx / 2304;
    const int s = idx % 2304;
    const int pp = s % 9;
    const int c = (s / 9) % 64;
    const int b = s / 576;
    const int pi = pp / 3, pj = pp % 3;
    const int hi = n / 3, wj = n % 3;
    const float val = p.x[((b * 64 + c) * 5 + (pi + hi)) * 5 + (pj + wj)];

    float sq[12];
#pragma unroll
    for (int e = 0; e < 12; ++e) sq[e] = p.ce[c * 12 + e] + p.pe[n * 12 + e] + val;

    float out[12];
#pragma unroll
    for (int r = 0; r < 12; ++r) {
      float acc = lb[r];
#pragma unroll
      for (int e = 0; e < 12; ++e) acc = fmaf(lw[r * 12 + e], sq[e], acc);
      out[r] = acc;
    }

    if (grp == 0) {
#pragma unroll
      for (int h = 0; h < 4; ++h) {
        ushort4 qq;
        qq.x = f2b(out[h * 3 + 0] * QSCALE);
        qq.y = f2b(out[h * 3 + 1] * QSCALE);
        qq.z = f2b(out[h * 3 + 2] * QSCALE);
        qq.w = 0;
        *(ushort4*)(p.Qb + ((size_t)(n * 4 + h) * SS + s) * 4) = qq;
      }
    } else if (grp == 1) {
#pragma unroll
      for (int h = 0; h < 4; ++h) {
        ushort4 kk;
        kk.x = f2b(out[h * 3 + 0]);
        kk.y = f2b(out[h * 3 + 1]);
        kk.z = f2b(out[h * 3 + 2]);
        kk.w = 0;
        *(ushort4*)(p.Kb + ((size_t)(n * 4 + h) * SS + s) * 4) = kk;
      }
    } else {
#pragma unroll
      for (int h = 0; h < 4; ++h) {
        const size_t vb = (size_t)((n * 4 + h) * 4) * SS + s;
        p.Vt[vb + 0 * SS] = f2b(out[h * 3 + 0]);
        p.Vt[vb + 1 * SS] = f2b(out[h * 3 + 1]);
        p.Vt[vb + 2 * SS] = f2b(out[h * 3 + 2]);
        p.Vt[vb + 3 * SS] = 0x3F80;  // ones row -> sum_exp rides in acc[3]
      }
    }
  }

  __threadfence();
  grid.sync();

  // ---------------- Phase 2: MFMA flash attention, grid-stride tasks ------
  const int lane = tid & 63;
  const int wv = tid >> 6;
  const int h = lane >> 5;
  const int sl = lane & 31;
  union F { s8v v; unsigned int u[4]; };

  for (int task = bid; task < NTASK; task += gridDim.x) {
    const int tc = task & 3;
    const int schunk = (task >> 2) % 18;
    const int nh = task / 72;
    const int t0 = tc * TCH;

    __syncthreads();  // previous task's readers done before restaging
    {
      const uint4* sk = (const uint4*)(p.Kb + ((size_t)nh * SS + t0) * 4);
      for (int i = tid; i < 288; i += 256) ((uint4*)lds)[i] = sk[i];
      for (int i = tid; i < 288; i += 256) {
        const int r = i / 72, cc = i - r * 72;  // 72 uint4 per 576-ushort row
        *(uint4*)(lds + 2304 + r * 584 + cc * 8) =
            *(const uint4*)(p.Vt + (size_t)(nh * 4 + r) * SS + t0 + cc * 8);
      }
      if (tid < 4) *(uint4*)(lds + 4640 + tid * 8) = make_uint4(0, 0, 0, 0);
    }
    __syncthreads();

    const int s0 = (schunk * 4 + wv) * 32;

    F fq;
    {
      const uint2 qw = *(const uint2*)(p.Qb + ((size_t)nh * SS + s0 + sl) * 4);
      fq.u[0] = h ? 0u : qw.x;
      fq.u[1] = h ? 0u : qw.y;
      fq.u[2] = 0u;
      fq.u[3] = 0u;
    }

    int koff = h ? 4640 : sl * 4;
    const int kinc = h ? 0 : 128;      // 32 tokens * 4 ushorts
    int voff = (sl < 4) ? (2304 + sl * 584 + h * 8) : 4640;
    const int vinc = (sl < 4) ? 32 : 0;

    const f32x16 kz = {};
    f32x16 acc = {};
#pragma unroll 2
    for (int t = 0; t < TCH / 32; ++t) {
      F fa;
      const uint2 kw = *(const uint2*)(lds + koff);
      fa.u[0] = kw.x; fa.u[1] = kw.y; fa.u[2] = 0u; fa.u[3] = 0u;
      f32x16 sT = __builtin_amdgcn_mfma_f32_32x32x16_bf16(fa.v, fq.v, kz, 0, 0, 0);

      unsigned int c0, c1, c2, c3, d0, d1, d2, d3;
      {
        const float p0 = EXP2(sT[0]), p1 = EXP2(sT[1]), p2 = EXP2(sT[2]),
                    p3 = EXP2(sT[3]), p4 = EXP2(sT[4]), p5 = EXP2(sT[5]),
                    p6 = EXP2(sT[6]), p7 = EXP2(sT[7]);
        asm("v_cvt_pk_bf16_f32 %0, %1, %2" : "=v"(c0) : "v"(p0), "v"(p1));
        asm("v_cvt_pk_bf16_f32 %0, %1, %2" : "=v"(c1) : "v"(p2), "v"(p3));
        asm("v_cvt_pk_bf16_f32 %0, %1, %2" : "=v"(c2) : "v"(p4), "v"(p5));
        asm("v_cvt_pk_bf16_f32 %0, %1, %2" : "=v"(c3) : "v"(p6), "v"(p7));
      }
      {
        const float p8 = EXP2(sT[8]), p9 = EXP2(sT[9]), pa = EXP2(sT[10]),
                    pb = EXP2(sT[11]), pc = EXP2(sT[12]), pd = EXP2(sT[13]),
                    pe = EXP2(sT[14]), pf = EXP2(sT[15]);
        asm("v_cvt_pk_bf16_f32 %0, %1, %2" : "=v"(d0) : "v"(p8), "v"(p9));
        asm("v_cvt_pk_bf16_f32 %0, %1, %2" : "=v"(d1) : "v"(pa), "v"(pb));
        asm("v_cvt_pk_bf16_f32 %0, %1, %2" : "=v"(d2) : "v"(pc), "v"(pd));
        asm("v_cvt_pk_bf16_f32 %0, %1, %2" : "=v"(d3) : "v"(pe), "v"(pf));
      }
      asm("v_permlane32_swap_b32 %0, %1" : "+v"(c0), "+v"(c2));
      asm("v_permlane32_swap_b32 %0, %1" : "+v"(c1), "+v"(c3));
      asm("v_permlane32_swap_b32 %0, %1" : "+v"(d0), "+v"(d2));
      asm("v_permlane32_swap_b32 %0, %1" : "+v"(d1), "+v"(d3));
      F pb0; pb0.u[0] = c0; pb0.u[1] = c1; pb0.u[2] = c2; pb0.u[3] = c3;
      F pb1; pb1.u[0] = d0; pb1.u[1] = d1; pb1.u[2] = d2; pb1.u[3] = d3;

      F fv0, fv1;
      *(uint4*)fv0.u = *(const uint4*)(lds + voff);
      *(uint4*)fv1.u = *(const uint4*)(lds + voff + 16);
      acc = __builtin_amdgcn_mfma_f32_32x32x16_bf16(fv0.v, pb0.v, acc, 0, 0, 0);
      acc = __builtin_amdgcn_mfma_f32_32x32x16_bf16(fv1.v, pb1.v, acc, 0, 0, 0);

      koff += kinc;
      voff += vinc;
    }

    if (h == 0) {
      p.part[((size_t)(nh * TSPLIT + tc)) * SS + s0 + sl] =
          make_float4(acc[0], acc[1], acc[2], acc[3]);
    }
  }

  __threadfence();
  grid.sync();

  // ---------------- Phase 3: combine + MLP + fold ----------------
  if (bid < 256) {
    float* L = (float*)lds;            // 828 floats
    float* pvs = (float*)lds + 828;    // 81 floats (3636 B < 9344)
    for (int i = tid; i < 144; i += 256) L[i] = p.opw[i];
    for (int i = tid; i < 288; i += 256) {
      L[180 + i] = p.f1w[i];
      L[492 + i] = p.f2w[i];
    }
    if (tid < 12) {
      L[144 + tid] = p.opb[tid];
      L[156 + tid] = p.ln1w[tid];
      L[168 + tid] = p.ln1b[tid];
      L[780 + tid] = p.f2b[tid];
      L[792 + tid] = p.ln2w[tid];
      L[804 + tid] = p.ln2b[tid];
      L[816 + tid] = p.linw[tid];
    }
    if (tid < 24) L[468 + tid] = p.f1b[tid];
    __syncthreads();

    const int bc = bid;                // b*64 + c
    const int c = bc & 63;

    if (tid < 81) {
      const int n = tid / 9;
      const int pp = tid % 9;
      const int s = bc * 9 + pp;
      const int pi = pp / 3, pj = pp % 3;
      const int hi2 = n / 3, wj2 = n % 3;
      const float val = p.x[(bc * 5 + (pi + hi2)) * 5 + (pj + wj2)];

      float ctx[12];
#pragma unroll
      for (int hh = 0; hh < 4; ++hh) {
        const float4* pq = p.part + ((size_t)((n * 4 + hh) * TSPLIT)) * SS + s;
        float l = 0.f, a0 = 0.f, a1 = 0.f, a2 = 0.f;
#pragma unroll
        for (int t = 0; t < TSPLIT; ++t) {
          const float4 v = pq[(size_t)t * SS];
          a0 += v.x; a1 += v.y; a2 += v.z; l += v.w;
        }
        const float rl = 1.0f / l;
        ctx[hh * 3 + 0] = a0 * rl;
        ctx[hh * 3 + 1] = a1 * rl;
        ctx[hh * 3 + 2] = a2 * rl;
      }

      float x1[12];
#pragma unroll
      for (int e = 0; e < 12; ++e) {
        float acc = L[144 + e];
#pragma unroll
        for (int j = 0; j < 12; ++j) acc = fmaf(L[e * 12 + j], ctx[j], acc);
        const float seq_e = p.ce[c * 12 + e] + p.pe[n * 12 + e] + val;
        x1[e] = seq_e + acc;
      }

      float mu = 0.f;
#pragma unroll
      for (int e = 0; e < 12; ++e) mu += x1[e];
      mu *= (1.0f / 12.0f);
      float var = 0.f;
#pragma unroll
      for (int e = 0; e < 12; ++e) { const float d = x1[e] - mu; var = fmaf(d, d, var); }
      var *= (1.0f / 12.0f);
      float rs = rsqrtf(var + 1e-5f);
      float h1[12];
#pragma unroll
      for (int e = 0; e < 12; ++e) h1[e] = (x1[e] - mu) * rs * L[156 + e] + L[168 + e];

      float f[24];
#pragma unroll
      for (int r = 0; r < 24; ++r) {
        float acc = L[468 + r];
#pragma unroll
        for (int e = 0; e < 12; ++e) acc = fmaf(L[180 + r * 12 + e], h1[e], acc);
        f[r] = fmaxf(acc, 0.f);
      }
      float x2[12];
#pragma unroll
      for (int e = 0; e < 12; ++e) {
        float acc = L[780 + e];
#pragma unroll
        for (int r = 0; r < 24; ++r) acc = fmaf(L[492 + e * 24 + r], f[r], acc);
        x2[e] = h1[e] + acc;
      }

      mu = 0.f;
#pragma unroll
      for (int e = 0; e < 12; ++e) mu += x2[e];
      mu *= (1.0f / 12.0f);
      var = 0.f;
#pragma unroll
      for (int e = 0; e < 12; ++e) { const float d = x2[e] - mu; var = fmaf(d, d, var); }
      var *= (1.0f / 12.0f);
      rs = rsqrtf(var + 1e-5f);

      float pv = p.linb[0];
#pragma unroll
      for (int e = 0; e < 12; ++e) {
        const float h2v = (x2[e] - mu) * rs * L[792 + e] + L[804 + e];
        pv = fmaf(L[816 + e], h2v, pv);
      }
      pvs[tid] = pv;                   // pvs[n*9 + p]
    }
    __syncthreads();

    if (tid < 25) {
      const int hh = tid / 5, ww = tid % 5;
      float sum = 0.f;
#pragma unroll
      for (int i = 0; i < 3; ++i) {
        const int hi2 = hh - i;
        if (hi2 < 0 || hi2 > 2) continue;
#pragma unroll
        for (int j = 0; j < 3; ++j) {
          const int wj2 = ww - j;
          if (wj2 < 0 || wj2 > 2) continue;
          sum += pvs[(hi2 * 3 + wj2) * 9 + (i * 3 + j)];
        }
      }
      p.out[bc * 25 + tid] = sum;
    }
  }
}

extern "C" void kernel_launch(void* const* d_in, const int* in_sizes, int n_in,
                              void* d_out, int out_size, void* d_ws, size_t ws_size,
                              hipStream_t stream) {
  Prm prm;
  prm.x    = (const float*)d_in[0];
  prm.ce   = (const float*)d_in[1];
  prm.pe   = (const float*)d_in[2];
  prm.ipw  = (const float*)d_in[3];
  prm.ipb  = (const float*)d_in[4];
  prm.opw  = (const float*)d_in[5];
  prm.opb  = (const float*)d_in[6];
  prm.ln1w = (const float*)d_in[7];
  prm.ln1b = (const float*)d_in[8];
  prm.f1w  = (const float*)d_in[9];
  prm.f1b  = (const float*)d_in[10];
  prm.f2w  = (const float*)d_in[11];
  prm.f2b  = (const float*)d_in[12];
  prm.ln2w = (const float*)d_in[13];
  prm.ln2b = (const float*)d_in[14];
  prm.linw = (const float*)d_in[15];
  prm.linb = (const float*)d_in[16];

  // ws layout (bytes): Qb[0,663552) Kb[663552,1327104) Vt[1327104,1990656)
  //                    part[1990656,7299072)
  prm.Qb = (unsigned short*)d_ws;
  prm.Kb = prm.Qb + 331776;
  prm.Vt = prm.Kb + 331776;
  prm.part = (float4*)((char*)d_ws + 1990656);
  prm.out = (float*)d_out;

  // Runtime-sized cooperative grid: never exceed the device's co-residency
  // capacity (this is what silently killed the R5 launch at grid=864).
  int maxB = 0;
  (void)hipOccupancyMaxActiveBlocksPerMultiprocessor(&maxB, fused, 256, 0);
  if (maxB < 1) maxB = 1;
  int grid = maxB * 256;               // 256 CUs on MI355X
  if (grid > MAXGRID) grid = MAXGRID;
  if (grid < 256) grid = 256;          // phases 1/3 need >=256 blocks

  void* kargs[] = {(void*)&prm};
  hipLaunchCooperativeKernel((const void*)fused, dim3(grid), dim3(256), kargs,
                             0, stream);
}

// Round 7
// 81.391 us; speedup vs baseline: 3.2178x; 3.2178x over previous
//
#include <hip/hip_runtime.h>
#include <hip/hip_bf16.h>
#include <math.h>

// ---- problem constants ----
#define SS 2304       // S = B*C*K*K
#define QSCALE 0.8329506128860126f  // log2(e)/sqrt(3)
#define TSPLIT 4
#define TCH 576       // SS / TSPLIT

// INSTRUMENTATION (this round): K2 compute phase runs REP times so the
// dispatch exceeds the ~40us harness fills and surfaces in rocprof top-5.
// Output is identical for any REP >= 1.
#define REP 2

#if defined(__has_builtin)
#if __has_builtin(__builtin_amdgcn_exp2f)
#define EXP2(x) __builtin_amdgcn_exp2f(x)
#endif
#endif
#ifndef EXP2
#define EXP2(x) exp2f(x)
#endif

typedef short s8v __attribute__((ext_vector_type(8)));
typedef float f32x16 __attribute__((ext_vector_type(16)));

static __device__ __forceinline__ unsigned short f2b(float f) {
  __hip_bfloat16 h = __float2bfloat16(f);
  return __builtin_bit_cast(unsigned short, h);
}

// ============================================================
// K1: seq = ce[c]+pe[n]+x_val; one of {q,k,v} 12-row GEMV per thread.
// ============================================================
__global__ __launch_bounds__(256) void k1_embed_qkv(
    const float* __restrict__ x, const float* __restrict__ ce,
    const float* __restrict__ pe, const float* __restrict__ w,
    const float* __restrict__ bias, unsigned short* __restrict__ Qb,
    unsigned short* __restrict__ Kb, unsigned short* __restrict__ Vt) {
  __shared__ float lw[144];
  __shared__ float lb[12];
  const int tid = threadIdx.x;
  const int grp = blockIdx.x / 81;       // 0=q 1=k 2=v
  const int ib = blockIdx.x % 81;
  for (int i = tid; i < 144; i += 256) lw[i] = w[grp * 144 + i];
  if (tid < 12) lb[tid] = bias[grp * 12 + tid];
  __syncthreads();

  const int idx = ib * 256 + tid;        // n*2304 + s
  const int n = idx / 2304;
  const int s = idx % 2304;
  const int p = s % 9;
  const int c = (s / 9) % 64;
  const int b = s / 576;
  const int pi = p / 3, pj = p % 3;
  const int hi = n / 3, wj = n % 3;
  const float val = x[((b * 64 + c) * 5 + (pi + hi)) * 5 + (pj + wj)];

  float sq[12];
#pragma unroll
  for (int e = 0; e < 12; ++e) sq[e] = ce[c * 12 + e] + pe[n * 12 + e] + val;

  float out[12];
#pragma unroll
  for (int r = 0; r < 12; ++r) {
    float acc = lb[r];
#pragma unroll
    for (int e = 0; e < 12; ++e) acc = fmaf(lw[r * 12 + e], sq[e], acc);
    out[r] = acc;
  }

  if (grp == 0) {
#pragma unroll
    for (int h = 0; h < 4; ++h) {
      ushort4 qq;
      qq.x = f2b(out[h * 3 + 0] * QSCALE);
      qq.y = f2b(out[h * 3 + 1] * QSCALE);
      qq.z = f2b(out[h * 3 + 2] * QSCALE);
      qq.w = 0;
      *(ushort4*)(Qb + ((size_t)(n * 4 + h) * SS + s) * 4) = qq;
    }
  } else if (grp == 1) {
#pragma unroll
    for (int h = 0; h < 4; ++h) {
      ushort4 kk;
      kk.x = f2b(out[h * 3 + 0]);
      kk.y = f2b(out[h * 3 + 1]);
      kk.z = f2b(out[h * 3 + 2]);
      kk.w = 0;
      *(ushort4*)(Kb + ((size_t)(n * 4 + h) * SS + s) * 4) = kk;
    }
  } else {
#pragma unroll
    for (int h = 0; h < 4; ++h) {
      const size_t vb = (size_t)((n * 4 + h) * 4) * SS + s;
      Vt[vb + 0 * SS] = f2b(out[h * 3 + 0]);
      Vt[vb + 1 * SS] = f2b(out[h * 3 + 1]);
      Vt[vb + 2 * SS] = f2b(out[h * 3 + 2]);
      Vt[vb + 3 * SS] = 0x3F80;  // ones row -> sum_exp rides in acc[3]
    }
  }
}

// ============================================================
// K2: MFMA flash attention, t-split partials (unnormalized).
// Identical math to the passing R4 kernel; compute phase repeated REP
// times (idempotent) purely to surface this dispatch in rocprof.
// ============================================================
__global__ __launch_bounds__(256) void k2_attn(
    const unsigned short* __restrict__ Qb, const unsigned short* __restrict__ Kb,
    const unsigned short* __restrict__ Vt, float4* __restrict__ part) {
  __shared__ unsigned short lds[4672];
  const int tid = threadIdx.x;
  const int tc = blockIdx.x & 3;
  const int schunk = (blockIdx.x >> 2) % 18;
  const int nh = blockIdx.x / 72;
  const int t0 = tc * TCH;

  {
    const uint4* sk = (const uint4*)(Kb + ((size_t)nh * SS + t0) * 4);
    for (int i = tid; i < 288; i += 256) ((uint4*)lds)[i] = sk[i];
    for (int i = tid; i < 288; i += 256) {
      const int r = i / 72, cc = i - r * 72;   // 72 uint4 per 576-ushort row
      *(uint4*)(lds + 2304 + r * 584 + cc * 8) =
          *(const uint4*)(Vt + (size_t)(nh * 4 + r) * SS + t0 + cc * 8);
    }
    if (tid < 4) *(uint4*)(lds + 4640 + tid * 8) = make_uint4(0, 0, 0, 0);
  }
  __syncthreads();

  const int lane = tid & 63;
  const int wv = tid >> 6;
  const int h = lane >> 5;
  const int sl = lane & 31;
  const int s0 = (schunk * 4 + wv) * 32;

  union F { s8v v; unsigned int u[4]; };

  for (int rep = 0; rep < REP; ++rep) {
    // block CSE of the second (identical, pure-LDS-read) pass
    asm volatile("" ::: "memory");

    F fq;
    {
      const uint2 qw = *(const uint2*)(Qb + ((size_t)nh * SS + s0 + sl) * 4);
      fq.u[0] = h ? 0u : qw.x;
      fq.u[1] = h ? 0u : qw.y;
      fq.u[2] = 0u;
      fq.u[3] = 0u;
    }

    int koff = h ? 4640 : sl * 4;
    const int kinc = h ? 0 : 128;          // 32 tokens * 4 ushorts
    int voff = (sl < 4) ? (2304 + sl * 584 + h * 8) : 4640;
    const int vinc = (sl < 4) ? 32 : 0;

    const f32x16 kz = {};
    f32x16 acc = {};
#pragma unroll 2
    for (int t = 0; t < TCH / 32; ++t) {
      F fa;
      const uint2 kw = *(const uint2*)(lds + koff);
      fa.u[0] = kw.x; fa.u[1] = kw.y; fa.u[2] = 0u; fa.u[3] = 0u;
      f32x16 sT = __builtin_amdgcn_mfma_f32_32x32x16_bf16(fa.v, fq.v, kz, 0, 0, 0);

      unsigned int c0, c1, c2, c3, d0, d1, d2, d3;
      {
        const float p0 = EXP2(sT[0]), p1 = EXP2(sT[1]), p2 = EXP2(sT[2]),
                    p3 = EXP2(sT[3]), p4 = EXP2(sT[4]), p5 = EXP2(sT[5]),
                    p6 = EXP2(sT[6]), p7 = EXP2(sT[7]);
        asm("v_cvt_pk_bf16_f32 %0, %1, %2" : "=v"(c0) : "v"(p0), "v"(p1));
        asm("v_cvt_pk_bf16_f32 %0, %1, %2" : "=v"(c1) : "v"(p2), "v"(p3));
        asm("v_cvt_pk_bf16_f32 %0, %1, %2" : "=v"(c2) : "v"(p4), "v"(p5));
        asm("v_cvt_pk_bf16_f32 %0, %1, %2" : "=v"(c3) : "v"(p6), "v"(p7));
      }
      {
        const float p8 = EXP2(sT[8]), p9 = EXP2(sT[9]), pa = EXP2(sT[10]),
                    pb = EXP2(sT[11]), pc = EXP2(sT[12]), pd = EXP2(sT[13]),
                    pe = EXP2(sT[14]), pf = EXP2(sT[15]);
        asm("v_cvt_pk_bf16_f32 %0, %1, %2" : "=v"(d0) : "v"(p8), "v"(p9));
        asm("v_cvt_pk_bf16_f32 %0, %1, %2" : "=v"(d1) : "v"(pa), "v"(pb));
        asm("v_cvt_pk_bf16_f32 %0, %1, %2" : "=v"(d2) : "v"(pc), "v"(pd));
        asm("v_cvt_pk_bf16_f32 %0, %1, %2" : "=v"(d3) : "v"(pe), "v"(pf));
      }
      asm("v_permlane32_swap_b32 %0, %1" : "+v"(c0), "+v"(c2));
      asm("v_permlane32_swap_b32 %0, %1" : "+v"(c1), "+v"(c3));
      asm("v_permlane32_swap_b32 %0, %1" : "+v"(d0), "+v"(d2));
      asm("v_permlane32_swap_b32 %0, %1" : "+v"(d1), "+v"(d3));
      F pb0; pb0.u[0] = c0; pb0.u[1] = c1; pb0.u[2] = c2; pb0.u[3] = c3;
      F pb1; pb1.u[0] = d0; pb1.u[1] = d1; pb1.u[2] = d2; pb1.u[3] = d3;

      F fv0, fv1;
      *(uint4*)fv0.u = *(const uint4*)(lds + voff);
      *(uint4*)fv1.u = *(const uint4*)(lds + voff + 16);
      acc = __builtin_amdgcn_mfma_f32_32x32x16_bf16(fv0.v, pb0.v, acc, 0, 0, 0);
      acc = __builtin_amdgcn_mfma_f32_32x32x16_bf16(fv1.v, pb1.v, acc, 0, 0, 0);

      koff += kinc;
      voff += vinc;
    }

    if (h == 0) {
      part[((size_t)(nh * TSPLIT + tc)) * SS + s0 + sl] =
          make_float4(acc[0], acc[1], acc[2], acc[3]);
    }
  }
}

// ============================================================
// K3: combine partials -> ctx; out_proj; +seq; LN1; FF; LN2; linear; FOLD.
// ============================================================
__global__ __launch_bounds__(128) void k3_mlp_fold(
    const float4* __restrict__ part, const float* __restrict__ x,
    const float* __restrict__ ce, const float* __restrict__ pe,
    const float* __restrict__ opw, const float* __restrict__ opb,
    const float* __restrict__ ln1w, const float* __restrict__ ln1b,
    const float* __restrict__ f1w, const float* __restrict__ f1b,
    const float* __restrict__ f2w, const float* __restrict__ f2b,
    const float* __restrict__ ln2w, const float* __restrict__ ln2b,
    const float* __restrict__ linw, const float* __restrict__ linb,
    float* __restrict__ out) {
  __shared__ float L[828];
  __shared__ float pvs[81];
  const int tid = threadIdx.x;
  for (int i = tid; i < 144; i += 128) L[i] = opw[i];
  for (int i = tid; i < 288; i += 128) {
    L[180 + i] = f1w[i];
    L[492 + i] = f2w[i];
  }
  if (tid < 12) {
    L[144 + tid] = opb[tid];
    L[156 + tid] = ln1w[tid];
    L[168 + tid] = ln1b[tid];
    L[780 + tid] = f2b[tid];
    L[792 + tid] = ln2w[tid];
    L[804 + tid] = ln2b[tid];
    L[816 + tid] = linw[tid];
  }
  if (tid < 24) L[468 + tid] = f1b[tid];
  __syncthreads();

  const int bc = blockIdx.x;             // b*64 + c
  const int c = bc & 63;

  if (tid < 81) {
    const int n = tid / 9;
    const int p = tid % 9;
    const int s = bc * 9 + p;
    const int pi = p / 3, pj = p % 3;
    const int hi = n / 3, wj = n % 3;
    const float val = x[(bc * 5 + (pi + hi)) * 5 + (pj + wj)];

    float ctx[12];
#pragma unroll
    for (int h = 0; h < 4; ++h) {
      const float4* pp = part + ((size_t)((n * 4 + h) * TSPLIT)) * SS + s;
      float l = 0.f, a0 = 0.f, a1 = 0.f, a2 = 0.f;
#pragma unroll
      for (int t = 0; t < TSPLIT; ++t) {
        const float4 v = pp[(size_t)t * SS];
        a0 += v.x; a1 += v.y; a2 += v.z; l += v.w;
      }
      const float rl = 1.0f / l;
      ctx[h * 3 + 0] = a0 * rl;
      ctx[h * 3 + 1] = a1 * rl;
      ctx[h * 3 + 2] = a2 * rl;
    }

    float x1[12];
#pragma unroll
    for (int e = 0; e < 12; ++e) {
      float acc = L[144 + e];
#pragma unroll
      for (int j = 0; j < 12; ++j) acc = fmaf(L[e * 12 + j], ctx[j], acc);
      const float seq_e = ce[c * 12 + e] + pe[n * 12 + e] + val;
      x1[e] = seq_e + acc;
    }

    float mu = 0.f;
#pragma unroll
    for (int e = 0; e < 12; ++e) mu += x1[e];
    mu *= (1.0f / 12.0f);
    float var = 0.f;
#pragma unroll
    for (int e = 0; e < 12; ++e) { const float d = x1[e] - mu; var = fmaf(d, d, var); }
    var *= (1.0f / 12.0f);
    float rs = rsqrtf(var + 1e-5f);
    float h1[12];
#pragma unroll
    for (int e = 0; e < 12; ++e) h1[e] = (x1[e] - mu) * rs * L[156 + e] + L[168 + e];

    float f[24];
#pragma unroll
    for (int r = 0; r < 24; ++r) {
      float acc = L[468 + r];
#pragma unroll
      for (int e = 0; e < 12; ++e) acc = fmaf(L[180 + r * 12 + e], h1[e], acc);
      f[r] = fmaxf(acc, 0.f);
    }
    float x2[12];
#pragma unroll
    for (int e = 0; e < 12; ++e) {
      float acc = L[780 + e];
#pragma unroll
      for (int r = 0; r < 24; ++r) acc = fmaf(L[492 + e * 24 + r], f[r], acc);
      x2[e] = h1[e] + acc;
    }

    mu = 0.f;
#pragma unroll
    for (int e = 0; e < 12; ++e) mu += x2[e];
    mu *= (1.0f / 12.0f);
    var = 0.f;
#pragma unroll
    for (int e = 0; e < 12; ++e) { const float d = x2[e] - mu; var = fmaf(d, d, var); }
    var *= (1.0f / 12.0f);
    rs = rsqrtf(var + 1e-5f);

    float pv = linb[0];
#pragma unroll
    for (int e = 0; e < 12; ++e) {
      const float h2v = (x2[e] - mu) * rs * L[792 + e] + L[804 + e];
      pv = fmaf(L[816 + e], h2v, pv);
    }
    pvs[tid] = pv;                       // pvs[n*9 + p]
  }
  __syncthreads();

  if (tid < 25) {
    const int hh = tid / 5, ww = tid % 5;
    float sum = 0.f;
#pragma unroll
    for (int i = 0; i < 3; ++i) {
      const int hi = hh - i;
      if (hi < 0 || hi > 2) continue;
#pragma unroll
      for (int j = 0; j < 3; ++j) {
        const int wj = ww - j;
        if (wj < 0 || wj > 2) continue;
        sum += pvs[(hi * 3 + wj) * 9 + (i * 3 + j)];
      }
    }
    out[bc * 25 + tid] = sum;
  }
}

extern "C" void kernel_launch(void* const* d_in, const int* in_sizes, int n_in,
                              void* d_out, int out_size, void* d_ws, size_t ws_size,
                              hipStream_t stream) {
  const float* x    = (const float*)d_in[0];
  const float* ce   = (const float*)d_in[1];
  const float* pe   = (const float*)d_in[2];
  const float* ipw  = (const float*)d_in[3];
  const float* ipb  = (const float*)d_in[4];
  const float* opw  = (const float*)d_in[5];
  const float* opb  = (const float*)d_in[6];
  const float* ln1w = (const float*)d_in[7];
  const float* ln1b = (const float*)d_in[8];
  const float* f1w  = (const float*)d_in[9];
  const float* f1b  = (const float*)d_in[10];
  const float* f2w  = (const float*)d_in[11];
  const float* f2b  = (const float*)d_in[12];
  const float* ln2w = (const float*)d_in[13];
  const float* ln2b = (const float*)d_in[14];
  const float* linw = (const float*)d_in[15];
  const float* linb = (const float*)d_in[16];

  // ws layout (bytes): Qb[0,663552) Kb[663552,1327104) Vt[1327104,1990656)
  //                    part[1990656,7299072)
  unsigned short* Qb = (unsigned short*)d_ws;
  unsigned short* Kb = Qb + 331776;
  unsigned short* Vt = Kb + 331776;
  float4* part = (float4*)((char*)d_ws + 1990656);

  k1_embed_qkv<<<243, 256, 0, stream>>>(x, ce, pe, ipw, ipb, Qb, Kb, Vt);
  k2_attn<<<36 * 18 * TSPLIT, 256, 0, stream>>>(Qb, Kb, Vt, part);
  k3_mlp_fold<<<256, 128, 0, stream>>>(part, x, ce, pe, opw, opb, ln1w, ln1b,
                                       f1w, f1b, f2w, f2b, ln2w, ln2b, linw,
                                       linb, (float*)d_out);
}

// Round 8
// 50.658 us; speedup vs baseline: 5.1700x; 1.6067x over previous
//
#include <hip/hip_runtime.h>
#include <hip/hip_bf16.h>
#include <math.h>

// ---- problem constants ----
#define SS 2304       // S = B*C*K*K
#define QSCALE 0.8329506128860126f  // log2(e)/sqrt(3)
#define TSPLIT 4
#define TCH 576       // SS / TSPLIT

#if defined(__has_builtin)
#if __has_builtin(__builtin_amdgcn_exp2f)
#define EXP2(x) __builtin_amdgcn_exp2f(x)
#endif
#endif
#ifndef EXP2
#define EXP2(x) exp2f(x)
#endif

typedef short s8v __attribute__((ext_vector_type(8)));
typedef float f32x16 __attribute__((ext_vector_type(16)));

static __device__ __forceinline__ unsigned short f2b(float f) {
  __hip_bfloat16 h = __float2bfloat16(f);
  return __builtin_bit_cast(unsigned short, h);
}

// ============================================================
// K2': fused embed+QKV+flash-attention partials.
// block = (nh, schunk of 128 s, tc of 576 t); 2592 blocks, 256 thr.
// The block computes its OWN K/V (576 tokens, head nh) and Q (128 rows)
// into LDS — no global qkv staging, no separate K1 kernel.
// LDS (ushort idx): K [0,2304) tok*4 | V^T 4 rows @2304 stride 584
//   | Q [4672,5184) 128*4 | fw floats @5184 (ce 768|pe_n 12|W 108|b 9)
// part[(nh*TSPLIT+tc)*SS + s] = float4(o0,o1,o2,sum_exp) unnormalized.
// ============================================================
__global__ __launch_bounds__(256) void k2_fused(
    const float* __restrict__ x, const float* __restrict__ ce,
    const float* __restrict__ pe, const float* __restrict__ ipw,
    const float* __restrict__ ipb, float4* __restrict__ part) {
  __shared__ __align__(16) unsigned short lds[6984];
  float* fw = (float*)(lds + 5184);     // byte 10368, 16B aligned
  const int tid = threadIdx.x;
  const int tc = blockIdx.x & 3;
  const int schunk = (blockIdx.x >> 2) % 18;
  const int nh = blockIdx.x / 72;
  const int n = nh >> 2, hh = nh & 3;
  const int t0 = tc * TCH;

  // ---- stage weights (ce, pe[n], head-sliced W/b) ----
  for (int i = tid; i < 768; i += 256) fw[i] = ce[i];
  if (tid < 12) fw[768 + tid] = pe[n * 12 + tid];
  if (tid < 108) {                      // Wq 780..816 | Wk 816..852 | Wv 852..888
    const int grp = tid / 36, idx = tid % 36;
    fw[780 + tid] = ipw[(grp * 12 + hh * 3 + idx / 12) * 12 + idx % 12];
  }
  if (tid >= 128 && tid < 137) {        // bq 888 | bk 891 | bv 894
    const int j = tid - 128;
    fw[888 + j] = ipb[(j / 3) * 12 + hh * 3 + (j % 3)];
  }
  __syncthreads();

  const float* pen = fw + 768;

  // ---- embed K/V for this block's 576 tokens ----
  for (int tl = tid; tl < 576; tl += 256) {
    const int tg = t0 + tl;
    const int pp = tg % 9, c = (tg / 9) % 64, b = tg / 576;
    const float val =
        x[((b * 64 + c) * 5 + (pp / 3 + n / 3)) * 5 + (pp % 3 + n % 3)];
    float sq[12];
#pragma unroll
    for (int e = 0; e < 12; ++e) sq[e] = fw[c * 12 + e] + pen[e] + val;
    float kd[3], vd[3];
#pragma unroll
    for (int d = 0; d < 3; ++d) {
      float a1 = fw[891 + d], a2 = fw[894 + d];
#pragma unroll
      for (int e = 0; e < 12; ++e) {
        a1 = fmaf(fw[816 + d * 12 + e], sq[e], a1);   // k
        a2 = fmaf(fw[852 + d * 12 + e], sq[e], a2);   // v
      }
      kd[d] = a1; vd[d] = a2;
    }
    ushort4 kk;
    kk.x = f2b(kd[0]); kk.y = f2b(kd[1]); kk.z = f2b(kd[2]); kk.w = 0;
    *(ushort4*)(lds + tl * 4) = kk;
    lds[2304 + 0 * 584 + tl] = f2b(vd[0]);
    lds[2304 + 1 * 584 + tl] = f2b(vd[1]);
    lds[2304 + 2 * 584 + tl] = f2b(vd[2]);
    lds[2304 + 3 * 584 + tl] = 0x3F80;  // ones row -> sum_exp in acc[3]
  }

  // ---- embed Q for this block's 128 s-rows ----
  if (tid < 128) {
    const int s = schunk * 128 + tid;
    const int pp = s % 9, c = (s / 9) % 64, b = s / 576;
    const float val =
        x[((b * 64 + c) * 5 + (pp / 3 + n / 3)) * 5 + (pp % 3 + n % 3)];
    float sq[12];
#pragma unroll
    for (int e = 0; e < 12; ++e) sq[e] = fw[c * 12 + e] + pen[e] + val;
    float qd[3];
#pragma unroll
    for (int d = 0; d < 3; ++d) {
      float a = fw[888 + d];
#pragma unroll
      for (int e = 0; e < 12; ++e) a = fmaf(fw[780 + d * 12 + e], sq[e], a);
      qd[d] = a * QSCALE;
    }
    ushort4 qq;
    qq.x = f2b(qd[0]); qq.y = f2b(qd[1]); qq.z = f2b(qd[2]); qq.w = 0;
    *(ushort4*)(lds + 4672 + tid * 4) = qq;
  }
  __syncthreads();

  // ---- MFMA flash attention over 18 t-tiles ----
  const int lane = tid & 63;
  const int wv = tid >> 6;
  const int h = lane >> 5;
  const int sl = lane & 31;
  const int s0 = (schunk * 4 + wv) * 32;

  union F { s8v v; unsigned int u[4]; };

  F fq;
  {
    const uint2 qw = *(const uint2*)(lds + 4672 + (wv * 32 + sl) * 4);
    fq.u[0] = h ? 0u : qw.x;
    fq.u[1] = h ? 0u : qw.y;
    fq.u[2] = 0u;
    fq.u[3] = 0u;
  }

  // static per-lane bases; t-offsets are compile-time (full unroll)
  const int kbase = sl * 4;                              // h=1: dup read, ok (x0 weight)
  const int vbase = 2304 + (sl & 3) * 584 + h * 8;       // rows>=4 land in unread acc rows

  const f32x16 kz = {};
  f32x16 acc = {};
#pragma unroll
  for (int t = 0; t < 18; ++t) {
    F fa;
    const uint2 kw = *(const uint2*)(lds + kbase + t * 128);
    fa.u[0] = kw.x; fa.u[1] = kw.y; fa.u[2] = 0u; fa.u[3] = 0u;
    f32x16 sT = __builtin_amdgcn_mfma_f32_32x32x16_bf16(fa.v, fq.v, kz, 0, 0, 0);

    unsigned int c0, c1, c2, c3, d0, d1, d2, d3;
    {
      const float p0 = EXP2(sT[0]), p1 = EXP2(sT[1]), p2 = EXP2(sT[2]),
                  p3 = EXP2(sT[3]), p4 = EXP2(sT[4]), p5 = EXP2(sT[5]),
                  p6 = EXP2(sT[6]), p7 = EXP2(sT[7]);
      asm("v_cvt_pk_bf16_f32 %0, %1, %2" : "=v"(c0) : "v"(p0), "v"(p1));
      asm("v_cvt_pk_bf16_f32 %0, %1, %2" : "=v"(c1) : "v"(p2), "v"(p3));
      asm("v_cvt_pk_bf16_f32 %0, %1, %2" : "=v"(c2) : "v"(p4), "v"(p5));
      asm("v_cvt_pk_bf16_f32 %0, %1, %2" : "=v"(c3) : "v"(p6), "v"(p7));
    }
    {
      const float p8 = EXP2(sT[8]), p9 = EXP2(sT[9]), pa = EXP2(sT[10]),
                  pb = EXP2(sT[11]), pc = EXP2(sT[12]), pd = EXP2(sT[13]),
                  pe2 = EXP2(sT[14]), pf = EXP2(sT[15]);
      asm("v_cvt_pk_bf16_f32 %0, %1, %2" : "=v"(d0) : "v"(p8), "v"(p9));
      asm("v_cvt_pk_bf16_f32 %0, %1, %2" : "=v"(d1) : "v"(pa), "v"(pb));
      asm("v_cvt_pk_bf16_f32 %0, %1, %2" : "=v"(d2) : "v"(pc), "v"(pd));
      asm("v_cvt_pk_bf16_f32 %0, %1, %2" : "=v"(d3) : "v"(pe2), "v"(pf));
    }
    asm("v_permlane32_swap_b32 %0, %1" : "+v"(c0), "+v"(c2));
    asm("v_permlane32_swap_b32 %0, %1" : "+v"(c1), "+v"(c3));
    asm("v_permlane32_swap_b32 %0, %1" : "+v"(d0), "+v"(d2));
    asm("v_permlane32_swap_b32 %0, %1" : "+v"(d1), "+v"(d3));
    F pb0; pb0.u[0] = c0; pb0.u[1] = c1; pb0.u[2] = c2; pb0.u[3] = c3;
    F pb1; pb1.u[0] = d0; pb1.u[1] = d1; pb1.u[2] = d2; pb1.u[3] = d3;

    F fv0, fv1;
    *(uint4*)fv0.u = *(const uint4*)(lds + vbase + t * 32);
    *(uint4*)fv1.u = *(const uint4*)(lds + vbase + t * 32 + 16);
    acc = __builtin_amdgcn_mfma_f32_32x32x16_bf16(fv0.v, pb0.v, acc, 0, 0, 0);
    acc = __builtin_amdgcn_mfma_f32_32x32x16_bf16(fv1.v, pb1.v, acc, 0, 0, 0);
  }

  if (h == 0) {
    part[((size_t)(nh * TSPLIT + tc)) * SS + s0 + sl] =
        make_float4(acc[0], acc[1], acc[2], acc[3]);
  }
}

// ============================================================
// K3: combine partials -> ctx; out_proj; +seq; LN1; FF; LN2; linear; FOLD.
// block = one (b,c) pair: 81 tokens, 128 threads; 256 blocks.
// ============================================================
__global__ __launch_bounds__(128) void k3_mlp_fold(
    const float4* __restrict__ part, const float* __restrict__ x,
    const float* __restrict__ ce, const float* __restrict__ pe,
    const float* __restrict__ opw, const float* __restrict__ opb,
    const float* __restrict__ ln1w, const float* __restrict__ ln1b,
    const float* __restrict__ f1w, const float* __restrict__ f1b,
    const float* __restrict__ f2w, const float* __restrict__ f2b,
    const float* __restrict__ ln2w, const float* __restrict__ ln2b,
    const float* __restrict__ linw, const float* __restrict__ linb,
    float* __restrict__ out) {
  __shared__ float L[828];
  __shared__ float pvs[81];
  const int tid = threadIdx.x;
  for (int i = tid; i < 144; i += 128) L[i] = opw[i];
  for (int i = tid; i < 288; i += 128) {
    L[180 + i] = f1w[i];
    L[492 + i] = f2w[i];
  }
  if (tid < 12) {
    L[144 + tid] = opb[tid];
    L[156 + tid] = ln1w[tid];
    L[168 + tid] = ln1b[tid];
    L[780 + tid] = f2b[tid];
    L[792 + tid] = ln2w[tid];
    L[804 + tid] = ln2b[tid];
    L[816 + tid] = linw[tid];
  }
  if (tid < 24) L[468 + tid] = f1b[tid];
  __syncthreads();

  const int bc = blockIdx.x;             // b*64 + c
  const int c = bc & 63;

  if (tid < 81) {
    const int n = tid / 9;
    const int p = tid % 9;
    const int s = bc * 9 + p;
    const int pi = p / 3, pj = p % 3;
    const int hi = n / 3, wj = n % 3;
    const float val = x[(bc * 5 + (pi + hi)) * 5 + (pj + wj)];

    float ctx[12];
#pragma unroll
    for (int h = 0; h < 4; ++h) {
      const float4* pp = part + ((size_t)((n * 4 + h) * TSPLIT)) * SS + s;
      float l = 0.f, a0 = 0.f, a1 = 0.f, a2 = 0.f;
#pragma unroll
      for (int t = 0; t < TSPLIT; ++t) {
        const float4 v = pp[(size_t)t * SS];
        a0 += v.x; a1 += v.y; a2 += v.z; l += v.w;
      }
      const float rl = 1.0f / l;
      ctx[h * 3 + 0] = a0 * rl;
      ctx[h * 3 + 1] = a1 * rl;
      ctx[h * 3 + 2] = a2 * rl;
    }

    float x1[12];
#pragma unroll
    for (int e = 0; e < 12; ++e) {
      float acc = L[144 + e];
#pragma unroll
      for (int j = 0; j < 12; ++j) acc = fmaf(L[e * 12 + j], ctx[j], acc);
      const float seq_e = ce[c * 12 + e] + pe[n * 12 + e] + val;
      x1[e] = seq_e + acc;
    }

    float mu = 0.f;
#pragma unroll
    for (int e = 0; e < 12; ++e) mu += x1[e];
    mu *= (1.0f / 12.0f);
    float var = 0.f;
#pragma unroll
    for (int e = 0; e < 12; ++e) { const float d = x1[e] - mu; var = fmaf(d, d, var); }
    var *= (1.0f / 12.0f);
    float rs = rsqrtf(var + 1e-5f);
    float h1[12];
#pragma unroll
    for (int e = 0; e < 12; ++e) h1[e] = (x1[e] - mu) * rs * L[156 + e] + L[168 + e];

    float f[24];
#pragma unroll
    for (int r = 0; r < 24; ++r) {
      float acc = L[468 + r];
#pragma unroll
      for (int e = 0; e < 12; ++e) acc = fmaf(L[180 + r * 12 + e], h1[e], acc);
      f[r] = fmaxf(acc, 0.f);
    }
    float x2[12];
#pragma unroll
    for (int e = 0; e < 12; ++e) {
      float acc = L[780 + e];
#pragma unroll
      for (int r = 0; r < 24; ++r) acc = fmaf(L[492 + e * 24 + r], f[r], acc);
      x2[e] = h1[e] + acc;
    }

    mu = 0.f;
#pragma unroll
    for (int e = 0; e < 12; ++e) mu += x2[e];
    mu *= (1.0f / 12.0f);
    var = 0.f;
#pragma unroll
    for (int e = 0; e < 12; ++e) { const float d = x2[e] - mu; var = fmaf(d, d, var); }
    var *= (1.0f / 12.0f);
    rs = rsqrtf(var + 1e-5f);

    float pv = linb[0];
#pragma unroll
    for (int e = 0; e < 12; ++e) {
      const float h2v = (x2[e] - mu) * rs * L[792 + e] + L[804 + e];
      pv = fmaf(L[816 + e], h2v, pv);
    }
    pvs[tid] = pv;                       // pvs[n*9 + p]
  }
  __syncthreads();

  if (tid < 25) {
    const int hh = tid / 5, ww = tid % 5;
    float sum = 0.f;
#pragma unroll
    for (int i = 0; i < 3; ++i) {
      const int hi = hh - i;
      if (hi < 0 || hi > 2) continue;
#pragma unroll
      for (int j = 0; j < 3; ++j) {
        const int wj = ww - j;
        if (wj < 0 || wj > 2) continue;
        sum += pvs[(hi * 3 + wj) * 9 + (i * 3 + j)];
      }
    }
    out[bc * 25 + tid] = sum;
  }
}

extern "C" void kernel_launch(void* const* d_in, const int* in_sizes, int n_in,
                              void* d_out, int out_size, void* d_ws, size_t ws_size,
                              hipStream_t stream) {
  const float* x    = (const float*)d_in[0];
  const float* ce   = (const float*)d_in[1];
  const float* pe   = (const float*)d_in[2];
  const float* ipw  = (const float*)d_in[3];
  const float* ipb  = (const float*)d_in[4];
  const float* opw  = (const float*)d_in[5];
  const float* opb  = (const float*)d_in[6];
  const float* ln1w = (const float*)d_in[7];
  const float* ln1b = (const float*)d_in[8];
  const float* f1w  = (const float*)d_in[9];
  const float* f1b  = (const float*)d_in[10];
  const float* f2w  = (const float*)d_in[11];
  const float* f2b  = (const float*)d_in[12];
  const float* ln2w = (const float*)d_in[13];
  const float* ln2b = (const float*)d_in[14];
  const float* linw = (const float*)d_in[15];
  const float* linb = (const float*)d_in[16];

  // ws layout (bytes): part [0, 36*4*2304*16 = 5308416)
  float4* part = (float4*)d_ws;

  k2_fused<<<36 * 18 * TSPLIT, 256, 0, stream>>>(x, ce, pe, ipw, ipb, part);
  k3_mlp_fold<<<256, 128, 0, stream>>>(part, x, ce, pe, opw, opb, ln1w, ln1b,
                                       f1w, f1b, f2w, f2b, ln2w, ln2b, linw,
                                       linb, (float*)d_out);
}

// Round 9
// 43.444 us; speedup vs baseline: 6.0285x; 1.1660x over previous
//
#include <hip/hip_runtime.h>
#include <hip/hip_bf16.h>
#include <math.h>

// ---- problem constants ----
#define SS 2304       // S = B*C*K*K
#define QSCALE 0.8329506128860126f  // log2(e)/sqrt(3)
#define TSPLIT 4
#define TCH 576       // SS / TSPLIT
#define SCH 9         // s-chunks of 256 rows

#if defined(__has_builtin)
#if __has_builtin(__builtin_amdgcn_exp2f)
#define EXP2(x) __builtin_amdgcn_exp2f(x)
#endif
#endif
#ifndef EXP2
#define EXP2(x) exp2f(x)
#endif

typedef short s8v __attribute__((ext_vector_type(8)));
typedef float f32x16 __attribute__((ext_vector_type(16)));

static __device__ __forceinline__ unsigned short f2b(float f) {
  __hip_bfloat16 h = __float2bfloat16(f);
  return __builtin_bit_cast(unsigned short, h);
}

// ============================================================
// K2': fused embed+QKV+flash-attention partials.
// block = (nh, schunk of 256 s, tc of 576 t); 36*9*4 = 1296 blocks x 512 thr.
// Each block embeds its own K/V (576 tokens) and Q (256 rows) into LDS.
// LDS (ushort idx): K [0,2304) tok*4 | V^T rows @2304 stride 584
//   | Q [4640,5664) 256*4 | fw floats @5664: ce+pe_n [0,768) | Wq/Wk/Wv
//   [780,888) | bq/bk/bv [888,897)
// part[(nh*TSPLIT+tc)*SS + s] = float4(o0,o1,o2,sum_exp) unnormalized.
// ============================================================
__global__ __launch_bounds__(512) void k2_fused(
    const float* __restrict__ x, const float* __restrict__ ce,
    const float* __restrict__ pe, const float* __restrict__ ipw,
    const float* __restrict__ ipb, float4* __restrict__ part) {
  __shared__ __align__(16) unsigned short lds[7458];
  float* fw = (float*)(lds + 5664);     // byte 11328, 16B aligned
  const int tid = threadIdx.x;
  const int tc = blockIdx.x & 3;
  const int schunk = (blockIdx.x >> 2) % SCH;
  const int nh = blockIdx.x / 36;
  const int n = nh >> 2, hh = nh & 3;
  const int t0 = tc * TCH;

  // ---- stage weights: ce+pe[n] folded, head-sliced W/b ----
  for (int i = tid; i < 768; i += 512) {
    const int e = i - (i / 12) * 12;
    fw[i] = ce[i] + pe[n * 12 + e];
  }
  if (tid < 108) {                      // Wq 780..816 | Wk 816..852 | Wv 852..888
    const int grp = tid / 36, idx = tid % 36;
    fw[780 + tid] = ipw[(grp * 12 + hh * 3 + idx / 12) * 12 + idx % 12];
  }
  if (tid >= 128 && tid < 137) {        // bq 888 | bk 891 | bv 894
    const int j = tid - 128;
    fw[888 + j] = ipb[(j / 3) * 12 + hh * 3 + (j % 3)];
  }
  __syncthreads();

  // ---- embed K/V for this block's 576 tokens ----
  for (int tl = tid; tl < 576; tl += 512) {
    const int tg = t0 + tl;
    const int pp = tg % 9, c = (tg / 9) % 64, b = tg / 576;
    const float val =
        x[((b * 64 + c) * 5 + (pp / 3 + n / 3)) * 5 + (pp % 3 + n % 3)];
    float sq[12];
#pragma unroll
    for (int e = 0; e < 12; ++e) sq[e] = fw[c * 12 + e] + val;
    float kd[3], vd[3];
#pragma unroll
    for (int d = 0; d < 3; ++d) {
      float a1 = fw[891 + d], a2 = fw[894 + d];
#pragma unroll
      for (int e = 0; e < 12; ++e) {
        a1 = fmaf(fw[816 + d * 12 + e], sq[e], a1);   // k
        a2 = fmaf(fw[852 + d * 12 + e], sq[e], a2);   // v
      }
      kd[d] = a1; vd[d] = a2;
    }
    ushort4 kk;
    kk.x = f2b(kd[0]); kk.y = f2b(kd[1]); kk.z = f2b(kd[2]); kk.w = 0;
    *(ushort4*)(lds + tl * 4) = kk;
    lds[2304 + 0 * 584 + tl] = f2b(vd[0]);
    lds[2304 + 1 * 584 + tl] = f2b(vd[1]);
    lds[2304 + 2 * 584 + tl] = f2b(vd[2]);
    lds[2304 + 3 * 584 + tl] = 0x3F80;  // ones row -> sum_exp in acc[3]
  }

  // ---- embed Q for this block's 256 s-rows ----
  if (tid < 256) {
    const int s = schunk * 256 + tid;
    const int pp = s % 9, c = (s / 9) % 64, b = s / 576;
    const float val =
        x[((b * 64 + c) * 5 + (pp / 3 + n / 3)) * 5 + (pp % 3 + n % 3)];
    float sq[12];
#pragma unroll
    for (int e = 0; e < 12; ++e) sq[e] = fw[c * 12 + e] + val;
    float qd[3];
#pragma unroll
    for (int d = 0; d < 3; ++d) {
      float a = fw[888 + d];
#pragma unroll
      for (int e = 0; e < 12; ++e) a = fmaf(fw[780 + d * 12 + e], sq[e], a);
      qd[d] = a * QSCALE;
    }
    ushort4 qq;
    qq.x = f2b(qd[0]); qq.y = f2b(qd[1]); qq.z = f2b(qd[2]); qq.w = 0;
    *(ushort4*)(lds + 4640 + tid * 4) = qq;
  }
  __syncthreads();

  // ---- MFMA flash attention over 18 t-tiles ----
  const int lane = tid & 63;
  const int wv = tid >> 6;              // 0..7
  const int h = lane >> 5;
  const int sl = lane & 31;
  const int s0 = schunk * 256 + wv * 32;

  union F { s8v v; unsigned int u[4]; };

  F fq;
  {
    const uint2 qw = *(const uint2*)(lds + 4640 + (wv * 32 + sl) * 4);
    fq.u[0] = h ? 0u : qw.x;
    fq.u[1] = h ? 0u : qw.y;
    fq.u[2] = 0u;
    fq.u[3] = 0u;
  }

  // static per-lane bases; t-offsets compile-time (full unroll)
  const int kbase = sl * 4;                            // h=1: dup read (x0 weight)
  const int vbase = 2304 + (sl & 3) * 584 + h * 8;     // rows>=4 -> unread acc rows

  const f32x16 kz = {};
  f32x16 acc = {};
#pragma unroll
  for (int t = 0; t < 18; ++t) {
    F fa;
    const uint2 kw = *(const uint2*)(lds + kbase + t * 128);
    fa.u[0] = kw.x; fa.u[1] = kw.y; fa.u[2] = 0u; fa.u[3] = 0u;
    f32x16 sT = __builtin_amdgcn_mfma_f32_32x32x16_bf16(fa.v, fq.v, kz, 0, 0, 0);

    unsigned int c0, c1, c2, c3, d0, d1, d2, d3;
    {
      const float p0 = EXP2(sT[0]), p1 = EXP2(sT[1]), p2 = EXP2(sT[2]),
                  p3 = EXP2(sT[3]), p4 = EXP2(sT[4]), p5 = EXP2(sT[5]),
                  p6 = EXP2(sT[6]), p7 = EXP2(sT[7]);
      asm("v_cvt_pk_bf16_f32 %0, %1, %2" : "=v"(c0) : "v"(p0), "v"(p1));
      asm("v_cvt_pk_bf16_f32 %0, %1, %2" : "=v"(c1) : "v"(p2), "v"(p3));
      asm("v_cvt_pk_bf16_f32 %0, %1, %2" : "=v"(c2) : "v"(p4), "v"(p5));
      asm("v_cvt_pk_bf16_f32 %0, %1, %2" : "=v"(c3) : "v"(p6), "v"(p7));
    }
    {
      const float p8 = EXP2(sT[8]), p9 = EXP2(sT[9]), pa = EXP2(sT[10]),
                  pb = EXP2(sT[11]), pc = EXP2(sT[12]), pd = EXP2(sT[13]),
                  pe2 = EXP2(sT[14]), pf = EXP2(sT[15]);
      asm("v_cvt_pk_bf16_f32 %0, %1, %2" : "=v"(d0) : "v"(p8), "v"(p9));
      asm("v_cvt_pk_bf16_f32 %0, %1, %2" : "=v"(d1) : "v"(pa), "v"(pb));
      asm("v_cvt_pk_bf16_f32 %0, %1, %2" : "=v"(d2) : "v"(pc), "v"(pd));
      asm("v_cvt_pk_bf16_f32 %0, %1, %2" : "=v"(d3) : "v"(pe2), "v"(pf));
    }
    asm("v_permlane32_swap_b32 %0, %1" : "+v"(c0), "+v"(c2));
    asm("v_permlane32_swap_b32 %0, %1" : "+v"(c1), "+v"(c3));
    asm("v_permlane32_swap_b32 %0, %1" : "+v"(d0), "+v"(d2));
    asm("v_permlane32_swap_b32 %0, %1" : "+v"(d1), "+v"(d3));
    F pb0; pb0.u[0] = c0; pb0.u[1] = c1; pb0.u[2] = c2; pb0.u[3] = c3;
    F pb1; pb1.u[0] = d0; pb1.u[1] = d1; pb1.u[2] = d2; pb1.u[3] = d3;

    F fv0, fv1;
    *(uint4*)fv0.u = *(const uint4*)(lds + vbase + t * 32);
    *(uint4*)fv1.u = *(const uint4*)(lds + vbase + t * 32 + 16);
    acc = __builtin_amdgcn_mfma_f32_32x32x16_bf16(fv0.v, pb0.v, acc, 0, 0, 0);
    acc = __builtin_amdgcn_mfma_f32_32x32x16_bf16(fv1.v, pb1.v, acc, 0, 0, 0);
  }

  if (h == 0) {
    part[((size_t)(nh * TSPLIT + tc)) * SS + s0 + sl] =
        make_float4(acc[0], acc[1], acc[2], acc[3]);
  }
}

// ============================================================
// K3: combine partials -> ctx; out_proj; +seq; LN1; FF; LN2; linear; FOLD.
// block = one (b,c) pair: 81 tokens, 128 threads; 256 blocks.
// ============================================================
__global__ __launch_bounds__(128) void k3_mlp_fold(
    const float4* __restrict__ part, const float* __restrict__ x,
    const float* __restrict__ ce, const float* __restrict__ pe,
    const float* __restrict__ opw, const float* __restrict__ opb,
    const float* __restrict__ ln1w, const float* __restrict__ ln1b,
    const float* __restrict__ f1w, const float* __restrict__ f1b,
    const float* __restrict__ f2w, const float* __restrict__ f2b,
    const float* __restrict__ ln2w, const float* __restrict__ ln2b,
    const float* __restrict__ linw, const float* __restrict__ linb,
    float* __restrict__ out) {
  __shared__ float L[828];
  __shared__ float pvs[81];
  const int tid = threadIdx.x;
  for (int i = tid; i < 144; i += 128) L[i] = opw[i];
  for (int i = tid; i < 288; i += 128) {
    L[180 + i] = f1w[i];
    L[492 + i] = f2w[i];
  }
  if (tid < 12) {
    L[144 + tid] = opb[tid];
    L[156 + tid] = ln1w[tid];
    L[168 + tid] = ln1b[tid];
    L[780 + tid] = f2b[tid];
    L[792 + tid] = ln2w[tid];
    L[804 + tid] = ln2b[tid];
    L[816 + tid] = linw[tid];
  }
  if (tid < 24) L[468 + tid] = f1b[tid];
  __syncthreads();

  const int bc = blockIdx.x;             // b*64 + c
  const int c = bc & 63;

  if (tid < 81) {
    const int n = tid / 9;
    const int p = tid % 9;
    const int s = bc * 9 + p;
    const int pi = p / 3, pj = p % 3;
    const int hi = n / 3, wj = n % 3;
    const float val = x[(bc * 5 + (pi + hi)) * 5 + (pj + wj)];

    float ctx[12];
#pragma unroll
    for (int h = 0; h < 4; ++h) {
      const float4* pp = part + ((size_t)((n * 4 + h) * TSPLIT)) * SS + s;
      float l = 0.f, a0 = 0.f, a1 = 0.f, a2 = 0.f;
#pragma unroll
      for (int t = 0; t < TSPLIT; ++t) {
        const float4 v = pp[(size_t)t * SS];
        a0 += v.x; a1 += v.y; a2 += v.z; l += v.w;
      }
      const float rl = 1.0f / l;
      ctx[h * 3 + 0] = a0 * rl;
      ctx[h * 3 + 1] = a1 * rl;
      ctx[h * 3 + 2] = a2 * rl;
    }

    float x1[12];
#pragma unroll
    for (int e = 0; e < 12; ++e) {
      float acc = L[144 + e];
#pragma unroll
      for (int j = 0; j < 12; ++j) acc = fmaf(L[e * 12 + j], ctx[j], acc);
      const float seq_e = ce[c * 12 + e] + pe[n * 12 + e] + val;
      x1[e] = seq_e + acc;
    }

    float mu = 0.f;
#pragma unroll
    for (int e = 0; e < 12; ++e) mu += x1[e];
    mu *= (1.0f / 12.0f);
    float var = 0.f;
#pragma unroll
    for (int e = 0; e < 12; ++e) { const float d = x1[e] - mu; var = fmaf(d, d, var); }
    var *= (1.0f / 12.0f);
    float rs = rsqrtf(var + 1e-5f);
    float h1[12];
#pragma unroll
    for (int e = 0; e < 12; ++e) h1[e] = (x1[e] - mu) * rs * L[156 + e] + L[168 + e];

    float f[24];
#pragma unroll
    for (int r = 0; r < 24; ++r) {
      float acc = L[468 + r];
#pragma unroll
      for (int e = 0; e < 12; ++e) acc = fmaf(L[180 + r * 12 + e], h1[e], acc);
      f[r] = fmaxf(acc, 0.f);
    }
    float x2[12];
#pragma unroll
    for (int e = 0; e < 12; ++e) {
      float acc = L[780 + e];
#pragma unroll
      for (int r = 0; r < 24; ++r) acc = fmaf(L[492 + e * 24 + r], f[r], acc);
      x2[e] = h1[e] + acc;
    }

    mu = 0.f;
#pragma unroll
    for (int e = 0; e < 12; ++e) mu += x2[e];
    mu *= (1.0f / 12.0f);
    var = 0.f;
#pragma unroll
    for (int e = 0; e < 12; ++e) { const float d = x2[e] - mu; var = fmaf(d, d, var); }
    var *= (1.0f / 12.0f);
    rs = rsqrtf(var + 1e-5f);

    float pv = linb[0];
#pragma unroll
    for (int e = 0; e < 12; ++e) {
      const float h2v = (x2[e] - mu) * rs * L[792 + e] + L[804 + e];
      pv = fmaf(L[816 + e], h2v, pv);
    }
    pvs[tid] = pv;                       // pvs[n*9 + p]
  }
  __syncthreads();

  if (tid < 25) {
    const int hh = tid / 5, ww = tid % 5;
    float sum = 0.f;
#pragma unroll
    for (int i = 0; i < 3; ++i) {
      const int hi = hh - i;
      if (hi < 0 || hi > 2) continue;
#pragma unroll
      for (int j = 0; j < 3; ++j) {
        const int wj = ww - j;
        if (wj < 0 || wj > 2) continue;
        sum += pvs[(hi * 3 + wj) * 9 + (i * 3 + j)];
      }
    }
    out[bc * 25 + tid] = sum;
  }
}

extern "C" void kernel_launch(void* const* d_in, const int* in_sizes, int n_in,
                              void* d_out, int out_size, void* d_ws, size_t ws_size,
                              hipStream_t stream) {
  const float* x    = (const float*)d_in[0];
  const float* ce   = (const float*)d_in[1];
  const float* pe   = (const float*)d_in[2];
  const float* ipw  = (const float*)d_in[3];
  const float* ipb  = (const float*)d_in[4];
  const float* opw  = (const float*)d_in[5];
  const float* opb  = (const float*)d_in[6];
  const float* ln1w = (const float*)d_in[7];
  const float* ln1b = (const float*)d_in[8];
  const float* f1w  = (const float*)d_in[9];
  const float* f1b  = (const float*)d_in[10];
  const float* f2w  = (const float*)d_in[11];
  const float* f2b  = (const float*)d_in[12];
  const float* ln2w = (const float*)d_in[13];
  const float* ln2b = (const float*)d_in[14];
  const float* linw = (const float*)d_in[15];
  const float* linb = (const float*)d_in[16];

  // ws layout (bytes): part [0, 36*4*2304*16 = 5308416)
  float4* part = (float4*)d_ws;

  k2_fused<<<36 * SCH * TSPLIT, 512, 0, stream>>>(x, ce, pe, ipw, ipb, part);
  k3_mlp_fold<<<256, 128, 0, stream>>>(part, x, ce, pe, opw, opb, ln1w, ln1b,
                                       f1w, f1b, f2w, f2b, ln2w, ln2b, linw,
                                       linb, (float*)d_out);
}

// Round 10
// 39.808 us; speedup vs baseline: 6.5791x; 1.0913x over previous
//
#include <hip/hip_runtime.h>
#include <hip/hip_bf16.h>
#include <math.h>

// ---- problem constants ----
#define SS 2304       // S = B*C*K*K
#define QSCALE 0.8329506128860126f  // log2(e)/sqrt(3)
#define TSPLIT 3
#define TCH 768       // SS / TSPLIT
#define SCH 9         // s-chunks of 256 rows
// grid = 36*9*3 = 972 blocks x 8 waves: single co-resident pass (<=1024)

#if defined(__has_builtin)
#if __has_builtin(__builtin_amdgcn_exp2f)
#define EXP2(x) __builtin_amdgcn_exp2f(x)
#endif
#endif
#ifndef EXP2
#define EXP2(x) exp2f(x)
#endif

// LDS layout (ushort idx):
//   K   [0,    3072)  768 tok * 4
//   V^T [3072, 6176)  4 rows, stride 776 (768 + 8 pad)
//   Q   [6176, 7200)  256 rows * 4
//   fw  [7200, 8994)  897 floats: ce+pe_n [0,768) | Wq/Wk/Wv [780,888) | b [888,897)
#define LK 0
#define LV 3072
#define LVS 776
#define LQ 6176
#define LF 7200

typedef short s8v __attribute__((ext_vector_type(8)));
typedef float f32x16 __attribute__((ext_vector_type(16)));

static __device__ __forceinline__ unsigned short f2b(float f) {
  __hip_bfloat16 h = __float2bfloat16(f);
  return __builtin_bit_cast(unsigned short, h);
}

// ============================================================
// K2': fused embed+QKV+flash-attention partials.
// block = (nh, schunk of 256 s, tc of 768 t); 972 blocks x 512 thr.
// part[(nh*TSPLIT+tc)*SS + s] = float4(o0,o1,o2,sum_exp) unnormalized.
// ============================================================
__global__ __launch_bounds__(512) void k2_fused(
    const float* __restrict__ x, const float* __restrict__ ce,
    const float* __restrict__ pe, const float* __restrict__ ipw,
    const float* __restrict__ ipb, float4* __restrict__ part) {
  __shared__ __align__(16) unsigned short lds[8994];
  float* fw = (float*)(lds + LF);       // byte 14400, 16B aligned
  const int tid = threadIdx.x;
  const int tc = blockIdx.x % TSPLIT;
  const int schunk = (blockIdx.x / TSPLIT) % SCH;
  const int nh = blockIdx.x / (TSPLIT * SCH);
  const int n = nh >> 2, hh = nh & 3;
  const int t0 = tc * TCH;

  // ---- stage weights: ce+pe[n] folded, head-sliced W/b ----
  for (int i = tid; i < 768; i += 512) {
    const int e = i - (i / 12) * 12;
    fw[i] = ce[i] + pe[n * 12 + e];
  }
  if (tid < 108) {                      // Wq 780..816 | Wk 816..852 | Wv 852..888
    const int grp = tid / 36, idx = tid % 36;
    fw[780 + tid] = ipw[(grp * 12 + hh * 3 + idx / 12) * 12 + idx % 12];
  }
  if (tid >= 128 && tid < 137) {        // bq 888 | bk 891 | bv 894
    const int j = tid - 128;
    fw[888 + j] = ipb[(j / 3) * 12 + hh * 3 + (j % 3)];
  }
  __syncthreads();

  // ---- embed K/V for this block's 768 tokens ----
  for (int tl = tid; tl < TCH; tl += 512) {
    const int tg = t0 + tl;
    const int pp = tg % 9, c = (tg / 9) % 64, b = tg / 576;
    const float val =
        x[((b * 64 + c) * 5 + (pp / 3 + n / 3)) * 5 + (pp % 3 + n % 3)];
    float sq[12];
#pragma unroll
    for (int e = 0; e < 12; ++e) sq[e] = fw[c * 12 + e] + val;
    float kd[3], vd[3];
#pragma unroll
    for (int d = 0; d < 3; ++d) {
      float a1 = fw[891 + d], a2 = fw[894 + d];
#pragma unroll
      for (int e = 0; e < 12; ++e) {
        a1 = fmaf(fw[816 + d * 12 + e], sq[e], a1);   // k
        a2 = fmaf(fw[852 + d * 12 + e], sq[e], a2);   // v
      }
      kd[d] = a1; vd[d] = a2;
    }
    ushort4 kk;
    kk.x = f2b(kd[0]); kk.y = f2b(kd[1]); kk.z = f2b(kd[2]); kk.w = 0;
    *(ushort4*)(lds + LK + tl * 4) = kk;
    lds[LV + 0 * LVS + tl] = f2b(vd[0]);
    lds[LV + 1 * LVS + tl] = f2b(vd[1]);
    lds[LV + 2 * LVS + tl] = f2b(vd[2]);
    lds[LV + 3 * LVS + tl] = 0x3F80;    // ones row -> sum_exp in acc[3]
  }

  // ---- embed Q for this block's 256 s-rows ----
  if (tid < 256) {
    const int s = schunk * 256 + tid;
    const int pp = s % 9, c = (s / 9) % 64, b = s / 576;
    const float val =
        x[((b * 64 + c) * 5 + (pp / 3 + n / 3)) * 5 + (pp % 3 + n % 3)];
    float sq[12];
#pragma unroll
    for (int e = 0; e < 12; ++e) sq[e] = fw[c * 12 + e] + val;
    float qd[3];
#pragma unroll
    for (int d = 0; d < 3; ++d) {
      float a = fw[888 + d];
#pragma unroll
      for (int e = 0; e < 12; ++e) a = fmaf(fw[780 + d * 12 + e], sq[e], a);
      qd[d] = a * QSCALE;
    }
    ushort4 qq;
    qq.x = f2b(qd[0]); qq.y = f2b(qd[1]); qq.z = f2b(qd[2]); qq.w = 0;
    *(ushort4*)(lds + LQ + tid * 4) = qq;
  }
  __syncthreads();

  // ---- MFMA flash attention over 24 t-tiles ----
  const int lane = tid & 63;
  const int wv = tid >> 6;              // 0..7
  const int h = lane >> 5;
  const int sl = lane & 31;
  const int s0 = schunk * 256 + wv * 32;

  union F { s8v v; unsigned int u[4]; };

  F fq;
  {
    const uint2 qw = *(const uint2*)(lds + LQ + (wv * 32 + sl) * 4);
    fq.u[0] = h ? 0u : qw.x;
    fq.u[1] = h ? 0u : qw.y;
    fq.u[2] = 0u;
    fq.u[3] = 0u;
  }

  // static per-lane bases; t-offsets compile-time (full unroll)
  const int kbase = LK + sl * 4;                       // h=1: dup read (x0 weight)
  const int vbase = LV + (sl & 3) * LVS + h * 8;       // rows>=4 -> unread acc rows

  const f32x16 kz = {};
  f32x16 acc = {};
#pragma unroll
  for (int t = 0; t < TCH / 32; ++t) {
    F fa;
    const uint2 kw = *(const uint2*)(lds + kbase + t * 128);
    fa.u[0] = kw.x; fa.u[1] = kw.y; fa.u[2] = 0u; fa.u[3] = 0u;
    f32x16 sT = __builtin_amdgcn_mfma_f32_32x32x16_bf16(fa.v, fq.v, kz, 0, 0, 0);

    unsigned int c0, c1, c2, c3, d0, d1, d2, d3;
    {
      const float p0 = EXP2(sT[0]), p1 = EXP2(sT[1]), p2 = EXP2(sT[2]),
                  p3 = EXP2(sT[3]), p4 = EXP2(sT[4]), p5 = EXP2(sT[5]),
                  p6 = EXP2(sT[6]), p7 = EXP2(sT[7]);
      asm("v_cvt_pk_bf16_f32 %0, %1, %2" : "=v"(c0) : "v"(p0), "v"(p1));
      asm("v_cvt_pk_bf16_f32 %0, %1, %2" : "=v"(c1) : "v"(p2), "v"(p3));
      asm("v_cvt_pk_bf16_f32 %0, %1, %2" : "=v"(c2) : "v"(p4), "v"(p5));
      asm("v_cvt_pk_bf16_f32 %0, %1, %2" : "=v"(c3) : "v"(p6), "v"(p7));
    }
    {
      const float p8 = EXP2(sT[8]), p9 = EXP2(sT[9]), pa = EXP2(sT[10]),
                  pb = EXP2(sT[11]), pc = EXP2(sT[12]), pd = EXP2(sT[13]),
                  pe2 = EXP2(sT[14]), pf = EXP2(sT[15]);
      asm("v_cvt_pk_bf16_f32 %0, %1, %2" : "=v"(d0) : "v"(p8), "v"(p9));
      asm("v_cvt_pk_bf16_f32 %0, %1, %2" : "=v"(d1) : "v"(pa), "v"(pb));
      asm("v_cvt_pk_bf16_f32 %0, %1, %2" : "=v"(d2) : "v"(pc), "v"(pd));
      asm("v_cvt_pk_bf16_f32 %0, %1, %2" : "=v"(d3) : "v"(pe2), "v"(pf));
    }
    asm("v_permlane32_swap_b32 %0, %1" : "+v"(c0), "+v"(c2));
    asm("v_permlane32_swap_b32 %0, %1" : "+v"(c1), "+v"(c3));
    asm("v_permlane32_swap_b32 %0, %1" : "+v"(d0), "+v"(d2));
    asm("v_permlane32_swap_b32 %0, %1" : "+v"(d1), "+v"(d3));
    F pb0; pb0.u[0] = c0; pb0.u[1] = c1; pb0.u[2] = c2; pb0.u[3] = c3;
    F pb1; pb1.u[0] = d0; pb1.u[1] = d1; pb1.u[2] = d2; pb1.u[3] = d3;

    F fv0, fv1;
    *(uint4*)fv0.u = *(const uint4*)(lds + vbase + t * 32);
    *(uint4*)fv1.u = *(const uint4*)(lds + vbase + t * 32 + 16);
    acc = __builtin_amdgcn_mfma_f32_32x32x16_bf16(fv0.v, pb0.v, acc, 0, 0, 0);
    acc = __builtin_amdgcn_mfma_f32_32x32x16_bf16(fv1.v, pb1.v, acc, 0, 0, 0);
  }

  if (h == 0) {
    part[((size_t)(nh * TSPLIT + tc)) * SS + s0 + sl] =
        make_float4(acc[0], acc[1], acc[2], acc[3]);
  }
}

// ============================================================
// K3: combine partials -> ctx; out_proj; +seq; LN1; FF; LN2; linear; FOLD.
// block = one (b,c) pair: 81 tokens, 128 threads; 256 blocks.
// ============================================================
__global__ __launch_bounds__(128) void k3_mlp_fold(
    const float4* __restrict__ part, const float* __restrict__ x,
    const float* __restrict__ ce, const float* __restrict__ pe,
    const float* __restrict__ opw, const float* __restrict__ opb,
    const float* __restrict__ ln1w, const float* __restrict__ ln1b,
    const float* __restrict__ f1w, const float* __restrict__ f1b,
    const float* __restrict__ f2w, const float* __restrict__ f2b,
    const float* __restrict__ ln2w, const float* __restrict__ ln2b,
    const float* __restrict__ linw, const float* __restrict__ linb,
    float* __restrict__ out) {
  __shared__ float L[828];
  __shared__ float pvs[81];
  const int tid = threadIdx.x;
  for (int i = tid; i < 144; i += 128) L[i] = opw[i];
  for (int i = tid; i < 288; i += 128) {
    L[180 + i] = f1w[i];
    L[492 + i] = f2w[i];
  }
  if (tid < 12) {
    L[144 + tid] = opb[tid];
    L[156 + tid] = ln1w[tid];
    L[168 + tid] = ln1b[tid];
    L[780 + tid] = f2b[tid];
    L[792 + tid] = ln2w[tid];
    L[804 + tid] = ln2b[tid];
    L[816 + tid] = linw[tid];
  }
  if (tid < 24) L[468 + tid] = f1b[tid];
  __syncthreads();

  const int bc = blockIdx.x;             // b*64 + c
  const int c = bc & 63;

  if (tid < 81) {
    const int n = tid / 9;
    const int p = tid % 9;
    const int s = bc * 9 + p;
    const int pi = p / 3, pj = p % 3;
    const int hi = n / 3, wj = n % 3;
    const float val = x[(bc * 5 + (pi + hi)) * 5 + (pj + wj)];

    float ctx[12];
#pragma unroll
    for (int h = 0; h < 4; ++h) {
      const float4* pp = part + ((size_t)((n * 4 + h) * TSPLIT)) * SS + s;
      float l = 0.f, a0 = 0.f, a1 = 0.f, a2 = 0.f;
#pragma unroll
      for (int t = 0; t < TSPLIT; ++t) {
        const float4 v = pp[(size_t)t * SS];
        a0 += v.x; a1 += v.y; a2 += v.z; l += v.w;
      }
      const float rl = 1.0f / l;
      ctx[h * 3 + 0] = a0 * rl;
      ctx[h * 3 + 1] = a1 * rl;
      ctx[h * 3 + 2] = a2 * rl;
    }

    float x1[12];
#pragma unroll
    for (int e = 0; e < 12; ++e) {
      float acc = L[144 + e];
#pragma unroll
      for (int j = 0; j < 12; ++j) acc = fmaf(L[e * 12 + j], ctx[j], acc);
      const float seq_e = ce[c * 12 + e] + pe[n * 12 + e] + val;
      x1[e] = seq_e + acc;
    }

    float mu = 0.f;
#pragma unroll
    for (int e = 0; e < 12; ++e) mu += x1[e];
    mu *= (1.0f / 12.0f);
    float var = 0.f;
#pragma unroll
    for (int e = 0; e < 12; ++e) { const float d = x1[e] - mu; var = fmaf(d, d, var); }
    var *= (1.0f / 12.0f);
    float rs = rsqrtf(var + 1e-5f);
    float h1[12];
#pragma unroll
    for (int e = 0; e < 12; ++e) h1[e] = (x1[e] - mu) * rs * L[156 + e] + L[168 + e];

    float f[24];
#pragma unroll
    for (int r = 0; r < 24; ++r) {
      float acc = L[468 + r];
#pragma unroll
      for (int e = 0; e < 12; ++e) acc = fmaf(L[180 + r * 12 + e], h1[e], acc);
      f[r] = fmaxf(acc, 0.f);
    }
    float x2[12];
#pragma unroll
    for (int e = 0; e < 12; ++e) {
      float acc = L[780 + e];
#pragma unroll
      for (int r = 0; r < 24; ++r) acc = fmaf(L[492 + e * 24 + r], f[r], acc);
      x2[e] = h1[e] + acc;
    }

    mu = 0.f;
#pragma unroll
    for (int e = 0; e < 12; ++e) mu += x2[e];
    mu *= (1.0f / 12.0f);
    var = 0.f;
#pragma unroll
    for (int e = 0; e < 12; ++e) { const float d = x2[e] - mu; var = fmaf(d, d, var); }
    var *= (1.0f / 12.0f);
    rs = rsqrtf(var + 1e-5f);

    float pv = linb[0];
#pragma unroll
    for (int e = 0; e < 12; ++e) {
      const float h2v = (x2[e] - mu) * rs * L[792 + e] + L[804 + e];
      pv = fmaf(L[816 + e], h2v, pv);
    }
    pvs[tid] = pv;                       // pvs[n*9 + p]
  }
  __syncthreads();

  if (tid < 25) {
    const int hh = tid / 5, ww = tid % 5;
    float sum = 0.f;
#pragma unroll
    for (int i = 0; i < 3; ++i) {
      const int hi = hh - i;
      if (hi < 0 || hi > 2) continue;
#pragma unroll
      for (int j = 0; j < 3; ++j) {
        const int wj = ww - j;
        if (wj < 0 || wj > 2) continue;
        sum += pvs[(hi * 3 + wj) * 9 + (i * 3 + j)];
      }
    }
    out[bc * 25 + tid] = sum;
  }
}

extern "C" void kernel_launch(void* const* d_in, const int* in_sizes, int n_in,
                              void* d_out, int out_size, void* d_ws, size_t ws_size,
                              hipStream_t stream) {
  const float* x    = (const float*)d_in[0];
  const float* ce   = (const float*)d_in[1];
  const float* pe   = (const float*)d_in[2];
  const float* ipw  = (const float*)d_in[3];
  const float* ipb  = (const float*)d_in[4];
  const float* opw  = (const float*)d_in[5];
  const float* opb  = (const float*)d_in[6];
  const float* ln1w = (const float*)d_in[7];
  const float* ln1b = (const float*)d_in[8];
  const float* f1w  = (const float*)d_in[9];
  const float* f1b  = (const float*)d_in[10];
  const float* f2w  = (const float*)d_in[11];
  const float* f2b  = (const float*)d_in[12];
  const float* ln2w = (const float*)d_in[13];
  const float* ln2b = (const float*)d_in[14];
  const float* linw = (const float*)d_in[15];
  const float* linb = (const float*)d_in[16];

  // ws layout (bytes): part [0, 36*3*2304*16 = 3981312)
  float4* part = (float4*)d_ws;

  k2_fused<<<36 * SCH * TSPLIT, 512, 0, stream>>>(x, ce, pe, ipw, ipb, part);
  k3_mlp_fold<<<256, 128, 0, stream>>>(part, x, ce, pe, opw, opb, ln1w, ln1b,
                                       f1w, f1b, f2w, f2b, ln2w, ln2b, linw,
                                       linb, (float*)d_out);
}